// Round 1
// baseline (365.275 us; speedup 1.0000x reference)
//
#include <hip/hip_runtime.h>

#define NN 4096
#define SCALE 0.35355339059327373f
#define CLAMPV 80.0f

// ws layout (floats):
//   qf  [B][8][N]   @ 0        (65536)
//   kf  [B][8][N]   @ 65536    (65536)
//   vf  [B][64][N]  @ 131072   (524288)
//   sinv[B][N]      @ 655360   (8192)

__global__ void qkv_kernel(const float* __restrict__ x,
                           const float* __restrict__ wq, const float* __restrict__ bq,
                           const float* __restrict__ wk, const float* __restrict__ bk,
                           const float* __restrict__ wv, const float* __restrict__ bv,
                           float* __restrict__ qf, float* __restrict__ kf,
                           float* __restrict__ vf) {
  __shared__ float xt[64][64];
  __shared__ float wvs[64][64];
  __shared__ float wqs[8][64];
  __shared__ float wks[8][64];
  int t = threadIdx.x;
  int b = blockIdx.x >> 6;
  int n0 = (blockIdx.x & 63) << 6;
  for (int i = t; i < 4096; i += 256) {
    int c = i >> 6, j = i & 63;
    xt[c][j] = x[((b * 64 + c) << 12) + n0 + j];
    wvs[c][j] = wv[i];
  }
  for (int i = t; i < 512; i += 256) {
    ((float*)wqs)[i] = wq[i];
    ((float*)wks)[i] = wk[i];
  }
  __syncthreads();
  for (int p = t; p < 5120; p += 256) {
    int r = p >> 6, j = p & 63;   // r uniform within a wave
    const float* wrow;
    float bias;
    float* dst;
    if (r < 8)       { wrow = wqs[r];      bias = bq[r];      dst = qf + ((b * 8 + r) << 12); }
    else if (r < 16) { wrow = wks[r - 8];  bias = bk[r - 8];  dst = kf + ((b * 8 + (r - 8)) << 12); }
    else             { wrow = wvs[r - 16]; bias = bv[r - 16]; dst = vf + ((b * 64 + (r - 16)) << 12); }
    float acc = bias;
    #pragma unroll
    for (int c = 0; c < 64; ++c) acc += wrow[c] * xt[c][j];
    dst[n0 + j] = acc;
  }
}

__global__ void rowsum_kernel(const float* __restrict__ qf, const float* __restrict__ kf,
                              float* __restrict__ sinv) {
  __shared__ float kt[256][8];   // m-major so one m's 8 k-values are a 32B run
  int t = threadIdx.x;
  int b = blockIdx.x >> 7;
  int n0 = (blockIdx.x & 127) << 5;
  int n = n0 + (t >> 3);
  int sub = t & 7;
  float qv[8];
  #pragma unroll
  for (int o = 0; o < 8; ++o) qv[o] = qf[((b * 8 + o) << 12) + n];
  float acc = 0.f;
  for (int mt = 0; mt < 4096; mt += 256) {
    __syncthreads();
    #pragma unroll
    for (int i = 0; i < 8; ++i) {
      // t covers m=0..255 coalesced; i is the o-row
      kt[t][i] = kf[((b * 8 + i) << 12) + mt + t];
    }
    __syncthreads();
    #pragma unroll 4
    for (int s = 0; s < 32; ++s) {
      int mm = sub + (s << 3);
      float4 ka = *(const float4*)&kt[mm][0];
      float4 kb = *(const float4*)&kt[mm][4];
      float l = qv[0] * ka.x + qv[1] * ka.y + qv[2] * ka.z + qv[3] * ka.w
              + qv[4] * kb.x + qv[5] * kb.y + qv[6] * kb.z + qv[7] * kb.w;
      l = fminf(fmaxf(l * SCALE, -CLAMPV), CLAMPV);
      acc += __expf(l);
    }
  }
  acc += __shfl_xor(acc, 1);
  acc += __shfl_xor(acc, 2);
  acc += __shfl_xor(acc, 4);
  if (sub == 0) sinv[(b << 12) + n] = 1.0f / acc;
}

__global__ void attnout_kernel(const float* __restrict__ x,
                               const float* __restrict__ qf, const float* __restrict__ kf,
                               const float* __restrict__ vf, const float* __restrict__ sinv,
                               const float* __restrict__ gamma,
                               float* __restrict__ out) {
  __shared__ float qn[8][64];
  __shared__ float wT[32][68];   // [m][n] pad->68 keeps 16B row alignment, 4-way max conflict
  __shared__ float vst[64][64];
  int t = threadIdx.x;
  int b = blockIdx.x >> 7;
  int m0 = (blockIdx.x & 127) << 5;
  int mi = t & 31;
  int g = t >> 5;                // 0..7 ; owns channels 8g..8g+7
  float kv[8];
  #pragma unroll
  for (int o = 0; o < 8; ++o) kv[o] = kf[((b * 8 + o) << 12) + m0 + mi];
  float acc[8];
  #pragma unroll
  for (int j = 0; j < 8; ++j) acc[j] = 0.f;

  for (int nt = 0; nt < NN; nt += 64) {
    __syncthreads();
    for (int i = t; i < 512; i += 256) {
      int o = i >> 6, j = i & 63;
      qn[o][j] = qf[((b * 8 + o) << 12) + nt + j];
    }
    for (int i = t; i < 4096; i += 256) {
      int c = i >> 6, j = i & 63;
      vst[c][j] = vf[((b * 64 + c) << 12) + nt + j] * sinv[(b << 12) + nt + j];
    }
    __syncthreads();
    // w[n][mi] = exp(clip(q[:,n].k[:,mi]*scale)) ; each thread does 8 n values
    #pragma unroll
    for (int s = 0; s < 8; ++s) {
      int n = (g << 3) + s;
      float l = 0.f;
      #pragma unroll
      for (int o = 0; o < 8; ++o) l += qn[o][n] * kv[o];
      l = fminf(fmaxf(l * SCALE, -CLAMPV), CLAMPV);
      wT[mi][n] = __expf(l);
    }
    __syncthreads();
    int c0 = g << 3;
    #pragma unroll
    for (int nq = 0; nq < 64; nq += 4) {
      float4 w4 = *(const float4*)&wT[mi][nq];
      #pragma unroll
      for (int j = 0; j < 8; ++j) {
        float4 vv = *(const float4*)&vst[c0 + j][nq];
        acc[j] += vv.x * w4.x + vv.y * w4.y + vv.z * w4.z + vv.w * w4.w;
      }
    }
  }
  float gm = gamma[0];
  #pragma unroll
  for (int j = 0; j < 8; ++j) {
    int c = (g << 3) + j;
    int idx = ((b * 64 + c) << 12) + m0 + mi;
    out[idx] = gm * acc[j] + x[idx];
  }
}

extern "C" void kernel_launch(void* const* d_in, const int* in_sizes, int n_in,
                              void* d_out, int out_size, void* d_ws, size_t ws_size,
                              hipStream_t stream) {
  const float* x     = (const float*)d_in[0];
  const float* wq    = (const float*)d_in[1];
  const float* bq    = (const float*)d_in[2];
  const float* wk    = (const float*)d_in[3];
  const float* bk    = (const float*)d_in[4];
  const float* wv    = (const float*)d_in[5];
  const float* bv    = (const float*)d_in[6];
  const float* gamma = (const float*)d_in[7];
  float* out = (float*)d_out;
  float* ws  = (float*)d_ws;
  float* qf   = ws;
  float* kf   = ws + 65536;
  float* vf   = ws + 131072;
  float* sinv = ws + 655360;

  qkv_kernel<<<128, 256, 0, stream>>>(x, wq, bq, wk, bk, wv, bv, qf, kf, vf);
  rowsum_kernel<<<256, 256, 0, stream>>>(qf, kf, sinv);
  attnout_kernel<<<256, 256, 0, stream>>>(x, qf, kf, vf, sinv, gamma, out);
}

// Round 3
// 166.235 us; speedup vs baseline: 2.1973x; 2.1973x over previous
//
#include <hip/hip_runtime.h>

#define SCALE 0.35355339059327373f
#define CLAMPV 80.0f

using h2 = decltype(__builtin_amdgcn_cvt_pkrtz(0.0f, 0.0f));
static __device__ __forceinline__ h2 u2h(unsigned u) { return __builtin_bit_cast(h2, u); }
static __device__ __forceinline__ unsigned h2u(h2 h) { return __builtin_bit_cast(unsigned, h); }
static __device__ __forceinline__ unsigned pkf16(float a, float b) {
  return h2u(__builtin_amdgcn_cvt_pkrtz(a, b));
}

// ws layout (float offsets):
//   qf   [2][8][4096]   @ 0        (65536)
//   kf   [2][8][4096]   @ 65536    (65536)
//   vf   [2][64][4096]  @ 131072   (524288)
//   sinv [2][4096]      @ 655360   (8192)
//   v16  [2][64][2048]u @ 663552   (131072 floats = 262144 uints)
//   pout [8][2][64][4096] @ 794624 (4194304)

__global__ void qkv_kernel(const float* __restrict__ x,
                           const float* __restrict__ wq, const float* __restrict__ bq,
                           const float* __restrict__ wk, const float* __restrict__ bk,
                           const float* __restrict__ wv, const float* __restrict__ bv,
                           float* __restrict__ qf, float* __restrict__ kf,
                           float* __restrict__ vf) {
  __shared__ float xt[64][64];
  __shared__ float wvs[64][64];
  __shared__ float wqs[8][64];
  __shared__ float wks[8][64];
  int t = threadIdx.x;
  int b = blockIdx.x >> 6;
  int n0 = (blockIdx.x & 63) << 6;
  for (int i = t; i < 4096; i += 256) {
    int c = i >> 6, j = i & 63;
    xt[c][j] = x[((b * 64 + c) << 12) + n0 + j];
    wvs[c][j] = wv[i];
  }
  for (int i = t; i < 512; i += 256) {
    ((float*)wqs)[i] = wq[i];
    ((float*)wks)[i] = wk[i];
  }
  __syncthreads();
  for (int p = t; p < 5120; p += 256) {
    int r = p >> 6, j = p & 63;
    const float* wrow;
    float bias;
    float* dst;
    if (r < 8)       { wrow = wqs[r];      bias = bq[r];      dst = qf + ((b * 8 + r) << 12); }
    else if (r < 16) { wrow = wks[r - 8];  bias = bk[r - 8];  dst = kf + ((b * 8 + (r - 8)) << 12); }
    else             { wrow = wvs[r - 16]; bias = bv[r - 16]; dst = vf + ((b * 64 + (r - 16)) << 12); }
    float acc = bias;
    #pragma unroll
    for (int c = 0; c < 64; ++c) acc += wrow[c] * xt[c][j];
    dst[n0 + j] = acc;
  }
}

__global__ void pack_v16(const float* __restrict__ vf, unsigned* __restrict__ v16) {
  int i = blockIdx.x * 256 + threadIdx.x;   // 131072 float4 units
  float4 v = ((const float4*)vf)[i];
  uint2 o;
  o.x = pkf16(v.x, v.y);
  o.y = pkf16(v.z, v.w);
  ((uint2*)v16)[i] = o;
}

// sinv[b][n] = 1 / sum_m exp(clip(q[:,n].k[:,m]*scale))
__global__ void rowsum_kernel(const float* __restrict__ qf, const float* __restrict__ kf,
                              float* __restrict__ sinv) {
  __shared__ float ps[16][17];
  int t = threadIdx.x;
  int b = blockIdx.x >> 8;
  int nt0 = (blockIdx.x & 255) << 4;
  int tn = t & 15, tm = t >> 4;
  int n = nt0 + tn;
  float q[8];
  #pragma unroll
  for (int o = 0; o < 8; ++o) q[o] = qf[((b * 8 + o) << 12) + n];
  float acc = 0.f;
  int m0 = tm << 8;
  for (int m4 = m0; m4 < m0 + 256; m4 += 4) {
    float4 k4[8];
    #pragma unroll
    for (int o = 0; o < 8; ++o) k4[o] = *(const float4*)&kf[((b * 8 + o) << 12) + m4];
    float l0 = 0.f, l1 = 0.f, l2 = 0.f, l3 = 0.f;
    #pragma unroll
    for (int o = 0; o < 8; ++o) {
      l0 += q[o] * k4[o].x; l1 += q[o] * k4[o].y;
      l2 += q[o] * k4[o].z; l3 += q[o] * k4[o].w;
    }
    l0 = fminf(fmaxf(l0 * SCALE, -CLAMPV), CLAMPV);
    l1 = fminf(fmaxf(l1 * SCALE, -CLAMPV), CLAMPV);
    l2 = fminf(fmaxf(l2 * SCALE, -CLAMPV), CLAMPV);
    l3 = fminf(fmaxf(l3 * SCALE, -CLAMPV), CLAMPV);
    acc += __expf(l0) + __expf(l1) + __expf(l2) + __expf(l3);
  }
  ps[tn][tm] = acc;
  __syncthreads();
  if (t < 16) {
    float s = 0.f;
    #pragma unroll
    for (int j = 0; j < 16; ++j) s += ps[t][j];
    sinv[(b << 12) + nt0 + t] = 1.0f / s;
  }
}

// Block: (b, m-tile of 256, n-chunk of 512). 256 thr: tm=t>>3 (8 m's), tc=t&7 (8 c's).
// acc[8c][8m] f32; v,w as f16 pairs along n consumed by v_dot2_f32_f16.
__global__ void __launch_bounds__(256, 1)
attnout_kernel(const float* __restrict__ qf, const float* __restrict__ kf,
               const float* __restrict__ sinvp, const unsigned* __restrict__ v16,
               float* __restrict__ pout) {
  __shared__ unsigned vls[16384];  // v slice [64c][64 nb] swizzled, 64 KB
  __shared__ unsigned wls[16384];  // w tile [256m][16 nb] swizzled, 64 KB
  int t = threadIdx.x;
  int bid = blockIdx.x;
  int b  = bid >> 7;
  int mt = (bid >> 3) & 15;
  int nc = bid & 7;
  int m0 = mt << 8;
  int n0 = nc << 9;
  int tm = t >> 3, tc = t & 7;

  // stage v16 slice [c][n0..n0+512) -> vls, XOR-swizzled (key = c>>3)
  for (int i = t; i < 4096; i += 256) {
    int c = i >> 6, nb = i & 63;
    uint4 v = *(const uint4*)&v16[((b << 6) + c) * 2048 + (n0 >> 1) + (nb << 2)];
    *(uint4*)&vls[c * 256 + ((nb ^ (c >> 3)) << 2)] = v;
  }
  // kreg: f16 o-pairs for this thread's 8 m-columns
  unsigned kreg[4][8];
  #pragma unroll
  for (int op = 0; op < 4; ++op)
    #pragma unroll
    for (int mm = 0; mm < 8; ++mm) {
      int m = m0 + (tm << 3) + mm;
      float a = kf[((b * 8 + 2 * op) << 12) + m];
      float c2 = kf[((b * 8 + 2 * op + 1) << 12) + m];
      kreg[op][mm] = pkf16(a, c2);
    }
  float acc[8][8];
  #pragma unroll
  for (int i = 0; i < 8; ++i)
    #pragma unroll
    for (int j = 0; j < 8; ++j) acc[i][j] = 0.f;
  __syncthreads();

  for (int nt = 0; nt < 512; nt += 128) {
    // ---- w-compute: w[n][m] = exp(clip(q.k*scale))*sinv[n], f16 pairs along n ----
    #pragma unroll
    for (int g = 0; g < 2; ++g) {
      int nb8 = tc + (g << 3);              // n8-group within tile (0..15)
      int nglob = n0 + nt + (nb8 << 3);
      unsigned q2[4][8];
      #pragma unroll
      for (int op = 0; op < 4; ++op) {
        float4 qa = *(const float4*)&qf[((b * 8 + 2 * op) << 12) + nglob];
        float4 qb = *(const float4*)&qf[((b * 8 + 2 * op) << 12) + nglob + 4];
        float4 ra = *(const float4*)&qf[((b * 8 + 2 * op + 1) << 12) + nglob];
        float4 rb = *(const float4*)&qf[((b * 8 + 2 * op + 1) << 12) + nglob + 4];
        q2[op][0] = pkf16(qa.x, ra.x); q2[op][1] = pkf16(qa.y, ra.y);
        q2[op][2] = pkf16(qa.z, ra.z); q2[op][3] = pkf16(qa.w, ra.w);
        q2[op][4] = pkf16(qb.x, rb.x); q2[op][5] = pkf16(qb.y, rb.y);
        q2[op][6] = pkf16(qb.z, rb.z); q2[op][7] = pkf16(qb.w, rb.w);
      }
      float4 s0 = *(const float4*)&sinvp[(b << 12) + nglob];
      float4 s1 = *(const float4*)&sinvp[(b << 12) + nglob + 4];
      float sv[8] = {s0.x, s0.y, s0.z, s0.w, s1.x, s1.y, s1.z, s1.w};
      #pragma unroll
      for (int mm = 0; mm < 8; ++mm) {
        float l[8] = {0.f, 0.f, 0.f, 0.f, 0.f, 0.f, 0.f, 0.f};
        #pragma unroll
        for (int op = 0; op < 4; ++op)
          #pragma unroll
          for (int j = 0; j < 8; ++j)
            l[j] = __builtin_amdgcn_fdot2(u2h(kreg[op][mm]), u2h(q2[op][j]), l[j], false);
        unsigned w[4];
        #pragma unroll
        for (int p = 0; p < 4; ++p) {
          float e0 = __expf(fminf(fmaxf(l[2 * p] * SCALE, -CLAMPV), CLAMPV)) * sv[2 * p];
          float e1 = __expf(fminf(fmaxf(l[2 * p + 1] * SCALE, -CLAMPV), CLAMPV)) * sv[2 * p + 1];
          w[p] = pkf16(e0, e1);
        }
        uint4 wvq = {w[0], w[1], w[2], w[3]};
        *(uint4*)&wls[((tm << 3) + mm) * 64 + ((nb8 ^ tm) << 2)] = wvq;
      }
    }
    __syncthreads();
    // ---- PV: acc[c][m] += sum_n v[c][n] * w[n][m] ----
    int nbase = nt >> 3;
    for (int it = 0; it < 16; ++it) {
      uint4 wv[8], vv[8];
      #pragma unroll
      for (int mm = 0; mm < 8; ++mm)
        wv[mm] = *(const uint4*)&wls[((tm << 3) + mm) * 64 + ((it ^ tm) << 2)];
      #pragma unroll
      for (int cc = 0; cc < 8; ++cc)
        vv[cc] = *(const uint4*)&vls[((tc << 3) + cc) * 256 + (((nbase + it) ^ tc) << 2)];
      #pragma unroll
      for (int cc = 0; cc < 8; ++cc)
        #pragma unroll
        for (int mm = 0; mm < 8; ++mm) {
          float a = acc[cc][mm];
          a = __builtin_amdgcn_fdot2(u2h(vv[cc].x), u2h(wv[mm].x), a, false);
          a = __builtin_amdgcn_fdot2(u2h(vv[cc].y), u2h(wv[mm].y), a, false);
          a = __builtin_amdgcn_fdot2(u2h(vv[cc].z), u2h(wv[mm].z), a, false);
          a = __builtin_amdgcn_fdot2(u2h(vv[cc].w), u2h(wv[mm].w), a, false);
          acc[cc][mm] = a;
        }
    }
    __syncthreads();
  }
  // store partial: pout[nc][b][c][m]
  #pragma unroll
  for (int cc = 0; cc < 8; ++cc) {
    float4 o0 = {acc[cc][0], acc[cc][1], acc[cc][2], acc[cc][3]};
    float4 o1 = {acc[cc][4], acc[cc][5], acc[cc][6], acc[cc][7]};
    int base = (nc << 19) + (((b << 6) + (tc << 3) + cc) << 12) + m0 + (tm << 3);
    *(float4*)&pout[base] = o0;
    *(float4*)&pout[base + 4] = o1;
  }
}

__global__ void epilogue_kernel(const float* __restrict__ x, const float* __restrict__ pout,
                                const float* __restrict__ gamma, float* __restrict__ out) {
  int i = blockIdx.x * 256 + threadIdx.x;   // 131072 float4 units
  float4 a = ((const float4*)pout)[i];
  #pragma unroll
  for (int ncx = 1; ncx < 8; ++ncx) {
    float4 p = ((const float4*)pout)[ncx * 131072 + i];
    a.x += p.x; a.y += p.y; a.z += p.z; a.w += p.w;
  }
  float4 xv = ((const float4*)x)[i];
  float g = gamma[0];
  float4 o;
  o.x = g * a.x + xv.x; o.y = g * a.y + xv.y;
  o.z = g * a.z + xv.z; o.w = g * a.w + xv.w;
  ((float4*)out)[i] = o;
}

extern "C" void kernel_launch(void* const* d_in, const int* in_sizes, int n_in,
                              void* d_out, int out_size, void* d_ws, size_t ws_size,
                              hipStream_t stream) {
  const float* x     = (const float*)d_in[0];
  const float* wq    = (const float*)d_in[1];
  const float* bq    = (const float*)d_in[2];
  const float* wk    = (const float*)d_in[3];
  const float* bk    = (const float*)d_in[4];
  const float* wv    = (const float*)d_in[5];
  const float* bv    = (const float*)d_in[6];
  const float* gamma = (const float*)d_in[7];
  float* out = (float*)d_out;
  float* ws  = (float*)d_ws;
  float*    qf   = ws;
  float*    kf   = ws + 65536;
  float*    vf   = ws + 131072;
  float*    sinv = ws + 655360;
  unsigned* v16  = (unsigned*)(ws + 663552);
  float*    pout = ws + 794624;

  qkv_kernel<<<128, 256, 0, stream>>>(x, wq, bq, wk, bk, wv, bv, qf, kf, vf);
  pack_v16<<<512, 256, 0, stream>>>(vf, v16);
  rowsum_kernel<<<512, 256, 0, stream>>>(qf, kf, sinv);
  attnout_kernel<<<256, 256, 0, stream>>>(qf, kf, sinv, v16, pout);
  epilogue_kernel<<<512, 256, 0, stream>>>(x, pout, gamma, out);
}

// Round 4
// 89.207 us; speedup vs baseline: 4.0947x; 1.8635x over previous
//
#include <hip/hip_runtime.h>

#define SCALE 0.35355339059327373f
#define CLAMPV 80.0f

using h2 = decltype(__builtin_amdgcn_cvt_pkrtz(0.0f, 0.0f));
typedef _Float16 half8 __attribute__((ext_vector_type(8)));
typedef float f32x4 __attribute__((ext_vector_type(4)));

static __device__ __forceinline__ h2 u2h(unsigned u) { return __builtin_bit_cast(h2, u); }
static __device__ __forceinline__ unsigned pkf16(float a, float b) {
  return __builtin_bit_cast(unsigned, __builtin_amdgcn_cvt_pkrtz(a, b));
}
static __device__ __forceinline__ half8 u4h8(uint4 u) { return __builtin_bit_cast(half8, u); }

// ws layout (u32 offsets):
//   q4  [2][4096][4]u  @ 0       (32768)   8 f16 o-values per n
//   k4  [2][4096][4]u  @ 32768   (32768)   8 f16 o-values per m
//   v16 [2][64][2048]u @ 65536   (262144)  f16 n-pairs
//   sinv [2][4096] f32 @ 327680  (8192)

__global__ void qkv_kernel(const float* __restrict__ x,
                           const float* __restrict__ wq, const float* __restrict__ bq,
                           const float* __restrict__ wk, const float* __restrict__ bk,
                           const float* __restrict__ wv, const float* __restrict__ bv,
                           unsigned* __restrict__ q4, unsigned* __restrict__ k4,
                           unsigned* __restrict__ v16) {
  __shared__ float xt[64][64];
  __shared__ float wvs[64][64];
  __shared__ float wqs[8][64];
  __shared__ float wks[8][64];
  __shared__ float ot[80][64];
  int t = threadIdx.x;
  int b = blockIdx.x >> 6;
  int n0 = (blockIdx.x & 63) << 6;
  for (int i = t; i < 4096; i += 256) {
    int c = i >> 6, j = i & 63;
    xt[c][j] = x[((b * 64 + c) << 12) + n0 + j];
    wvs[c][j] = wv[i];
  }
  for (int i = t; i < 512; i += 256) {
    ((float*)wqs)[i] = wq[i];
    ((float*)wks)[i] = wk[i];
  }
  __syncthreads();
  for (int p = t; p < 5120; p += 256) {
    int r = p >> 6, j = p & 63;   // r uniform per wave
    const float* wrow;
    float bias;
    if (r < 8)       { wrow = wqs[r];      bias = bq[r]; }
    else if (r < 16) { wrow = wks[r - 8];  bias = bk[r - 8]; }
    else             { wrow = wvs[r - 16]; bias = bv[r - 16]; }
    float acc = bias;
    #pragma unroll
    for (int c = 0; c < 64; ++c) acc += wrow[c] * xt[c][j];
    ot[r][j] = acc;
  }
  __syncthreads();
  // pack q4 (wave 0) / k4 (wave 1)
  if (t < 128) {
    int j = t & 63;
    int row0 = (t < 64) ? 0 : 8;
    unsigned* dst = (t < 64) ? q4 : k4;
    uint4 u;
    u.x = pkf16(ot[row0 + 0][j], ot[row0 + 1][j]);
    u.y = pkf16(ot[row0 + 2][j], ot[row0 + 3][j]);
    u.z = pkf16(ot[row0 + 4][j], ot[row0 + 5][j]);
    u.w = pkf16(ot[row0 + 6][j], ot[row0 + 7][j]);
    *(uint4*)&dst[((b << 12) + n0 + j) << 2] = u;
  }
  // pack v16 (all threads): c = t>>2, quarter qd = t&3 -> 8 n-pairs
  {
    int c = t >> 2, qd = t & 3;
    unsigned uu[8];
    #pragma unroll
    for (int jj = 0; jj < 8; ++jj) {
      int j2 = qd * 8 + jj;
      uu[jj] = pkf16(ot[16 + c][2 * j2], ot[16 + c][2 * j2 + 1]);
    }
    unsigned* dst = &v16[(((b << 6) + c) << 11) + (n0 >> 1) + (qd << 3)];
    *(uint4*)&dst[0] = make_uint4(uu[0], uu[1], uu[2], uu[3]);
    *(uint4*)&dst[4] = make_uint4(uu[4], uu[5], uu[6], uu[7]);
  }
}

// sinv[b][n] = 1 / sum_m exp(clip(q.k*scale))
__global__ void rowsum_kernel(const unsigned* __restrict__ q4, const unsigned* __restrict__ k4,
                              float* __restrict__ sinv) {
  __shared__ float ps[16][17];
  int t = threadIdx.x;
  int b = blockIdx.x >> 8;
  int nt0 = (blockIdx.x & 255) << 4;
  int tn = t & 15, tg = t >> 4;
  uint4 qu = *(const uint4*)&q4[((b << 12) + nt0 + tn) << 2];
  h2 q0 = u2h(qu.x), q1 = u2h(qu.y), q2 = u2h(qu.z), q3 = u2h(qu.w);
  float acc = 0.f;
  int m0 = tg << 8;
  #pragma unroll 4
  for (int m = m0; m < m0 + 256; ++m) {
    uint4 ka = *(const uint4*)&k4[((b << 12) + m) << 2];
    float l = __builtin_amdgcn_fdot2(u2h(ka.x), q0, 0.f, false);
    l = __builtin_amdgcn_fdot2(u2h(ka.y), q1, l, false);
    l = __builtin_amdgcn_fdot2(u2h(ka.z), q2, l, false);
    l = __builtin_amdgcn_fdot2(u2h(ka.w), q3, l, false);
    l = fminf(fmaxf(l * SCALE, -CLAMPV), CLAMPV);
    acc += __expf(l);
  }
  ps[tn][tg] = acc;
  __syncthreads();
  if (t < 16) {
    float s = 0.f;
    #pragma unroll
    for (int j = 0; j < 16; ++j) s += ps[t][j];
    sinv[(b << 12) + nt0 + t] = 1.0f / s;
  }
}

// MFMA attention: block = (b, 32-m tile), 4 waves n-split (1024 n each).
// Per K-step (32 n): QK via 2x2 mfma_16x16x32_f16 (K=8 padded), exp/sinv on D-layout,
// in-wave relayout to B-frag via 2 ds_swizzle(xor16) + 6 cndmask; lane-group perm
// absorbed into v16 load address. PV: 8 mfma into f32 acc. Epilogue: LDS reduce + out.
__global__ void __launch_bounds__(256, 1)
attnout_kernel(const float* __restrict__ x, const unsigned* __restrict__ q4,
               const unsigned* __restrict__ k4, const unsigned* __restrict__ v16,
               const float* __restrict__ sinv, const float* __restrict__ gamma,
               float* __restrict__ out) {
  __shared__ float red[4][64][36];
  int t = threadIdx.x;
  int b = blockIdx.x >> 7;
  int m0 = (blockIdx.x & 127) << 5;
  int w = t >> 6, l = t & 63;
  int L15 = l & 15, G = l >> 4;
  int permG = ((G & 1) << 1) | (G >> 1);
  bool even = (G & 1) == 0;

  uint4 bk[2];
  #pragma unroll
  for (int mh = 0; mh < 2; ++mh) {
    if (l < 16) bk[mh] = *(const uint4*)&k4[((b << 12) + m0 + mh * 16 + L15) << 2];
    else        bk[mh] = make_uint4(0, 0, 0, 0);
  }
  f32x4 acc[2][4];
  #pragma unroll
  for (int mh = 0; mh < 2; ++mh)
    #pragma unroll
    for (int cf = 0; cf < 4; ++cf) acc[mh][cf] = (f32x4){0.f, 0.f, 0.f, 0.f};

  const float* svb = sinv + (b << 12);
  const unsigned* q4b = q4 + ((long)(b << 12) << 2);

  for (int step = 0; step < 32; ++step) {
    int n0 = (w << 10) + (step << 5);
    // A-frags for QK (lanes>=16 hold dup data; zeroed bk kills padded K slots)
    half8 aq0 = u4h8(*(const uint4*)&q4b[(n0 + L15) << 2]);
    half8 aq1 = u4h8(*(const uint4*)&q4b[(n0 + 16 + L15) << 2]);
    f32x4 sv0 = *(const f32x4*)&svb[n0 + (G << 2)];
    f32x4 sv1 = *(const f32x4*)&svb[n0 + 16 + (G << 2)];
    // v A-frags (shared by both m-halves); n-order permuted by permG
    uint4 va[4];
    #pragma unroll
    for (int cf = 0; cf < 4; ++cf)
      va[cf] = *(const uint4*)&v16[(((b << 6) + (cf << 4) + L15) << 11) + (n0 >> 1) + (permG << 2)];

    #pragma unroll
    for (int mh = 0; mh < 2; ++mh) {
      f32x4 z = {0.f, 0.f, 0.f, 0.f};
      f32x4 d0 = __builtin_amdgcn_mfma_f32_16x16x32_f16(aq0, u4h8(bk[mh]), z, 0, 0, 0);
      f32x4 d1 = __builtin_amdgcn_mfma_f32_16x16x32_f16(aq1, u4h8(bk[mh]), z, 0, 0, 0);
      float p0[4], p1[4];
      #pragma unroll
      for (int r = 0; r < 4; ++r) {
        float e0 = fminf(fmaxf(d0[r] * SCALE, -CLAMPV), CLAMPV);
        float e1 = fminf(fmaxf(d1[r] * SCALE, -CLAMPV), CLAMPV);
        p0[r] = __expf(e0) * sv0[r];
        p1[r] = __expf(e1) * sv1[r];
      }
      unsigned x0 = pkf16(p0[0], p0[1]), x1 = pkf16(p0[2], p0[3]);
      unsigned y0 = pkf16(p1[0], p1[1]), y1 = pkf16(p1[2], p1[3]);
      // exchange with lane^16: even lanes need neighbor's x, odd need neighbor's y
      unsigned snd0 = even ? y0 : x0;
      unsigned snd1 = even ? y1 : x1;
      unsigned r0 = (unsigned)__builtin_amdgcn_ds_swizzle((int)snd0, 0x401F);
      unsigned r1 = (unsigned)__builtin_amdgcn_ds_swizzle((int)snd1, 0x401F);
      uint4 Bu;
      Bu.x = even ? x0 : r0;
      Bu.y = even ? x1 : r1;
      Bu.z = even ? r0 : y0;
      Bu.w = even ? r1 : y1;
      half8 Bf = u4h8(Bu);
      #pragma unroll
      for (int cf = 0; cf < 4; ++cf)
        acc[mh][cf] = __builtin_amdgcn_mfma_f32_16x16x32_f16(u4h8(va[cf]), Bf, acc[mh][cf], 0, 0, 0);
    }
  }

  // cross-wave reduction over the 4 n-quarters
  #pragma unroll
  for (int mh = 0; mh < 2; ++mh)
    #pragma unroll
    for (int cf = 0; cf < 4; ++cf)
      *(f32x4*)&red[w][l][(mh * 4 + cf) * 4] = acc[mh][cf];
  __syncthreads();
  int rl = t & 63, fp = t >> 6;
  float g = gamma[0];
  #pragma unroll
  for (int ff = 0; ff < 2; ++ff) {
    int f = fp * 2 + ff;
    f32x4 s = {0.f, 0.f, 0.f, 0.f};
    #pragma unroll
    for (int ww = 0; ww < 4; ++ww) s += *(const f32x4*)&red[ww][rl][f * 4];
    int mh = f >> 2, cf = f & 3;
    int m = m0 + mh * 16 + (rl & 15);
    int cb = cf * 16 + ((rl >> 4) << 2);
    #pragma unroll
    for (int r = 0; r < 4; ++r) {
      int idx = (((b << 6) + cb + r) << 12) + m;
      out[idx] = g * s[r] + x[idx];
    }
  }
}

extern "C" void kernel_launch(void* const* d_in, const int* in_sizes, int n_in,
                              void* d_out, int out_size, void* d_ws, size_t ws_size,
                              hipStream_t stream) {
  const float* x     = (const float*)d_in[0];
  const float* wq    = (const float*)d_in[1];
  const float* bq    = (const float*)d_in[2];
  const float* wk    = (const float*)d_in[3];
  const float* bk    = (const float*)d_in[4];
  const float* wv    = (const float*)d_in[5];
  const float* bv    = (const float*)d_in[6];
  const float* gamma = (const float*)d_in[7];
  float* out = (float*)d_out;
  unsigned* wsu = (unsigned*)d_ws;
  unsigned* q4  = wsu;
  unsigned* k4  = wsu + 32768;
  unsigned* v16 = wsu + 65536;
  float*    sinv = (float*)(wsu + 327680);

  qkv_kernel<<<128, 256, 0, stream>>>(x, wq, bq, wk, bk, wv, bv, q4, k4, v16);
  rowsum_kernel<<<512, 256, 0, stream>>>(q4, k4, sinv);
  attnout_kernel<<<256, 256, 0, stream>>>(x, q4, k4, v16, sinv, gamma, out);
}